// Round 4
// baseline (383.284 us; speedup 1.0000x reference)
//
#include <hip/hip_runtime.h>
#include <stdint.h>

typedef unsigned short u16;
typedef unsigned int u32;
typedef __attribute__((ext_vector_type(8))) short short8;
typedef __attribute__((ext_vector_type(4))) short short4v;
typedef __attribute__((ext_vector_type(4))) float f32x4;

#define HW 64
#define CH 256
#define NIMG 16
#define NPIX (NIMG*HW*HW)   // 65536 pixels

static __device__ __forceinline__ u16 f2bf(float f){
  u32 u = __float_as_uint(f);
  u32 r = u + 0x7FFFu + ((u >> 16) & 1u);   // RNE
  return (u16)(r >> 16);
}
static __device__ __forceinline__ float bf2f(u16 h){
  return __uint_as_float(((u32)h) << 16);
}
static __device__ __forceinline__ u32 relu_pk(u32 w){   // relu two packed bf16
  u32 lo = (w & 0x00008000u) ? 0u : (w & 0x0000FFFFu);
  u32 hi = (w & 0x80000000u) ? 0u : (w & 0xFFFF0000u);
  return lo | hi;
}

// ---------------- weight prep: W1T[j][c], W2T[j][tap][c], bf16 ----------------
__global__ void k_prep(const float* __restrict__ w1, const float* __restrict__ w2,
                       u16* __restrict__ W1T, u16* __restrict__ W2T){
  int idx = blockIdx.x*256 + threadIdx.x;   // 640*256 = 163840 exactly
  if (idx < 16384){
    int j = idx >> 8, c = idx & 255;
    W1T[idx] = f2bf(w1[c*64 + j]);          // w1 is (1,1,256,64) -> [c][j]
  } else {
    int o = idx - 16384;
    int j = o / 2304;
    int rem = o - j*2304;
    int tap = rem >> 8, c = rem & 255;
    W2T[o] = f2bf(w2[(tap*256 + c)*64 + j]); // w2 is (3,3,256,64) -> [tap][c][j]
  }
}

// ---------------- phase 1: fused 4-step pointwise gradual update ----------------
// 64-px tiles (grid 1024), LDS 66 KB -> 2 blocks/CU. Wave owns 16 px; no inter-step barrier.
// Writes B = relu(final A).
__global__ __launch_bounds__(256) void k_phase1(const float* __restrict__ x,
    const u16* __restrict__ W1T, const float* __restrict__ b1, u16* __restrict__ B){
  __shared__ u16 At[64*264];
  __shared__ u16 Ws[64*264];
  const int tid = threadIdx.x;
  const long pbase = (long)blockIdx.x * 64;

  #pragma unroll
  for (int it=0; it<16; ++it){
    int idx = it*256 + tid;
    int px = idx >> 6;
    int c4 = (idx & 63) << 2;
    const float4 v = *(const float4*)(x + (pbase + px)*CH + c4);
    short4v s;
    s[0] = (short)f2bf(v.x); s[1] = (short)f2bf(v.y);
    s[2] = (short)f2bf(v.z); s[3] = (short)f2bf(v.w);
    *(short4v*)&At[px*264 + c4] = s;
  }
  #pragma unroll
  for (int it=0; it<8; ++it){
    int idx = it*256 + tid;
    int n = idx >> 5;
    int c8 = (idx & 31) << 3;
    *(uint4*)&Ws[n*264 + c8] = *(const uint4*)&W1T[n*256 + c8];
  }
  __syncthreads();

  const int wave = tid >> 6, lane = tid & 63;
  const int m = lane & 15, quad = lane >> 4;
  const int abase = (wave*16 + m)*264 + quad*8;
  int bbase[4];
  #pragma unroll
  for (int nt=0; nt<4; ++nt) bbase[nt] = (nt*16 + m)*264 + quad*8;
  float b1v[4];
  #pragma unroll
  for (int nt=0; nt<4; ++nt) b1v[nt] = b1[nt*16 + m];

  for (int stepi=0; stepi<4; ++stepi){
    f32x4 acc[4];
    #pragma unroll
    for (int b=0;b<4;++b) acc[b] = 0.f;
    #pragma unroll
    for (int kk=0; kk<8; ++kk){
      const int ko = kk*32;
      short8 af = *(const short8*)&At[abase + ko];
      short8 bf[4];
      #pragma unroll
      for (int nt=0; nt<4; ++nt) bf[nt] = *(const short8*)&Ws[bbase[nt] + ko];
      #pragma unroll
      for (int nt=0; nt<4; ++nt)
        acc[nt] = __builtin_amdgcn_mfma_f32_16x16x32_bf16(af, bf[nt], acc[nt], 0,0,0);
    }
    #pragma unroll
    for (int nt=0; nt<4; ++nt){
      #pragma unroll
      for (int r=0; r<4; ++r){
        int px = wave*16 + quad*4 + r;
        At[px*264 + stepi*64 + nt*16 + m] = f2bf(acc[nt][r] + b1v[nt]);
      }
    }
  }
  __syncthreads();
  #pragma unroll
  for (int it=0; it<16; ++it){
    int idx = it*256 + tid;
    int px = idx >> 6;
    int c4 = (idx & 63) << 2;
    uint2 v = *(const uint2*)&At[px*264 + c4];
    v.x = relu_pk(v.x); v.y = relu_pk(v.y);
    *(uint2*)&B[(pbase + px)*CH + c4] = v;
  }
}

// ---------------- phase 2: one 3x3 gradual-update step (launched 4x) ----------------
// 8x16 px tiles, grid 512, 256 threads (4 waves). LDS 53.6 KB -> 2 blocks/CU
// co-resident: sibling block covers barrier drains. Wave tile 32px x 64ch (mt=2).
__global__ __launch_bounds__(256,2) void k_phase2(const u16* __restrict__ B,
    u16* __restrict__ Bout, const u16* __restrict__ W2T, const float* __restrict__ b2,
    const int step){
  __shared__ u16 As[180*72];      // 10x18 halo px x 64 ch (+8 pad)  25920 B
  __shared__ u16 Ws[192*72];      // [dc*64+n] x 64 ch (+8 pad)      27648 B
  const int tid = threadIdx.x;
  const int bid = blockIdx.x;
  const int img = bid >> 5;
  const int R0 = ((bid >> 2) & 7) * 8;
  const int C0 = (bid & 3) * 16;

  const int wave = tid >> 6, lane = tid & 63;
  const int m = lane & 15, quad = lane >> 4;

  uint4 ra[6], rw[6];

  auto load_as = [&](int q){
    #pragma unroll
    for (int it=0; it<6; ++it){
      int idx = it*256 + tid;
      uint4 v = make_uint4(0u,0u,0u,0u);
      if (idx < 1440){
        int px = idx >> 3, ck = idx & 7;
        int hr = px / 18, hc = px - hr*18;
        int r = R0 + hr - 1, c = C0 + hc - 1;
        if ((unsigned)r < 64u && (unsigned)c < 64u){
          const u16* src = (q < step) ? Bout : B;   // B already relu'd by phase1
          v = *(const uint4*)&src[((((size_t)img*64)+r)*64 + c)*CH + q*64 + ck*8];
        }
      }
      ra[it] = v;
    }
  };
  auto store_as = [&](){
    #pragma unroll
    for (int it=0; it<6; ++it){
      int idx = it*256 + tid;
      if (idx < 1440){
        int px = idx >> 3, ck = idx & 7;
        *(uint4*)&As[px*72 + ck*8] = ra[it];
      }
    }
  };
  auto load_ws = [&](int q, int dr){
    #pragma unroll
    for (int it=0; it<6; ++it){
      int idx = it*256 + tid;                  // 1536 exact
      int row = idx >> 3, ck = idx & 7;        // row = dc*64 + n
      int dc = row >> 6, n = row & 63;
      rw[it] = *(const uint4*)&W2T[(size_t)n*2304 + (dr*3 + dc)*256 + q*64 + ck*8];
    }
  };
  auto store_ws = [&](){
    #pragma unroll
    for (int it=0; it<6; ++it){
      int idx = it*256 + tid;
      int row = idx >> 3, ck = idx & 7;
      *(uint4*)&Ws[row*72 + ck*8] = rw[it];
    }
  };

  // prologue: stage (q=0, dr=0)
  load_as(0); load_ws(0, 0);
  store_as(); store_ws();
  __syncthreads();

  f32x4 acc[2][4];
  #pragma unroll
  for (int a=0;a<2;++a){
    #pragma unroll
    for (int b=0;b<4;++b) acc[a][b] = 0.f;
  }

  int seg = 0;
  for (int q = 0; q < 4; ++q){
    for (int dr = 0; dr < 3; ++dr, ++seg){
      const bool last = (seg == 11);
      if (!last){
        if (dr < 2) load_ws(q, dr+1);
        else        load_ws(q+1, 0);
        if (dr == 2) load_as(q+1);
      }
      #pragma unroll
      for (int dc=0; dc<3; ++dc){
        #pragma unroll
        for (int kk=0; kk<2; ++kk){
          short8 af[2], bf[4];
          #pragma unroll
          for (int mt=0; mt<2; ++mt){
            int hr = 2*wave + mt + dr;
            af[mt] = *(const short8*)&As[(hr*18 + m + dc)*72 + kk*32 + quad*8];
          }
          #pragma unroll
          for (int nt=0; nt<4; ++nt)
            bf[nt] = *(const short8*)&Ws[(dc*64 + nt*16 + m)*72 + kk*32 + quad*8];
          #pragma unroll
          for (int mt=0; mt<2; ++mt){
            #pragma unroll
            for (int nt=0; nt<4; ++nt)
              acc[mt][nt] = __builtin_amdgcn_mfma_f32_16x16x32_bf16(af[mt], bf[nt], acc[mt][nt], 0,0,0);
          }
        }
      }
      if (!last){
        __syncthreads();
        store_ws();
        if (dr == 2) store_as();
        __syncthreads();
      }
    }
  }

  float b2v[4];
  #pragma unroll
  for (int nt=0; nt<4; ++nt) b2v[nt] = b2[nt*16 + m];
  #pragma unroll
  for (int mt=0; mt<2; ++mt){
    #pragma unroll
    for (int nt=0; nt<4; ++nt){
      #pragma unroll
      for (int r=0; r<4; ++r){
        int row = R0 + 2*wave + mt;
        int col = C0 + quad*4 + r;
        size_t gi = ((((size_t)img*64 + row)*64) + col)*CH + step*64 + nt*16 + m;
        Bout[gi] = f2bf(acc[mt][nt][r] + b2v[nt]);
      }
    }
  }
}

// ---------------- phase 3: per-pixel affine recurrence + residual ----------------
// 4 lanes per pixel, 64 ch each (d[8] = 32 VGPR, register-resident: no spill).
// A'_{i+1} = (1+w_i)A'_i - w_i a_i  affine in A'_0; quad-lane prefix via shuffles.
__global__ __launch_bounds__(256) void k_phase3(const u16* __restrict__ Bout,
    const float* __restrict__ w3, const float* __restrict__ b3,
    const float* __restrict__ x, float* __restrict__ out){
  __shared__ float w3s[256];
  const int tid = threadIdx.x;
  if (tid < 64) *(float4*)&w3s[tid*4] = *(const float4*)&w3[tid*4];
  const float b3v = b3[0];
  __syncthreads();

  const int g  = blockIdx.x*256 + tid;
  const int h  = g & 3;                      // quarter index within pixel
  const size_t cbase = (size_t)(g >> 2)*CH + h*64;
  const int wb = h*64;                       // w3s base for own quarter

  // load own 64 channels (relu'd), keep in registers
  uint4 d[8];
  #pragma unroll
  for (int i=0; i<8; ++i){
    uint4 v = *(const uint4*)&Bout[cbase + i*8];
    v.x = relu_pk(v.x); v.y = relu_pk(v.y); v.z = relu_pk(v.z); v.w = relu_pk(v.w);
    d[i] = v;
  }

  // single pass: partial dot + affine prefix (alpha,beta) over own quarter
  float s0=0.f, s1=0.f, alpha=1.f, beta=0.f;
  #pragma unroll
  for (int i=0; i<8; ++i){
    const u32* p = (const u32*)&d[i];
    #pragma unroll
    for (int k=0; k<4; ++k){
      u32 wv = p[k];
      int c = i*8 + k*2;
      float w_a = w3s[wb + c];
      float w_b = w3s[wb + c + 1];
      float a_a = bf2f((u16)(wv & 0xFFFF));
      float a_b = bf2f((u16)(wv >> 16));
      s0 += a_a * w_a;
      s1 += a_b * w_b;
      beta  = (1.f + w_a)*beta  - w_a*a_a;
      alpha = (1.f + w_a)*alpha;
      beta  = (1.f + w_b)*beta  - w_b*a_b;
      alpha = (1.f + w_b)*alpha;
    }
  }
  float dot = s0 + s1;
  dot += __shfl_xor(dot, 1);
  dot += __shfl_xor(dot, 2);                 // full-pixel dot at all 4 lanes
  float A0 = b3v + dot;                      // A'_0

  // compose prefixes of quarters < h
  const int lane = tid & 63;
  const int base = lane & ~3;
  float a0 = __shfl(alpha, base+0), b0 = __shfl(beta, base+0);
  float a1 = __shfl(alpha, base+1), b1_ = __shfl(beta, base+1);
  float a2 = __shfl(alpha, base+2), b2_ = __shfl(beta, base+2);
  float Ap = A0;
  if (h > 0) Ap = a0*Ap + b0;
  if (h > 1) Ap = a1*Ap + b1_;
  if (h > 2) Ap = a2*Ap + b2_;

  // output pass: out_c = A'_c + x_c ; A' <- (1+w)A' - w*a
  #pragma unroll
  for (int i=0; i<8; ++i){
    const u32* p = (const u32*)&d[i];
    float4 xv0 = *(const float4*)&x[cbase + i*8];
    float4 xv1 = *(const float4*)&x[cbase + i*8 + 4];
    float xs[8] = {xv0.x,xv0.y,xv0.z,xv0.w,xv1.x,xv1.y,xv1.z,xv1.w};
    float os[8];
    #pragma unroll
    for (int k=0; k<4; ++k){
      u32 wv = p[k];
      int c = i*8 + k*2;
      float w_a = w3s[wb + c];
      float w_b = w3s[wb + c + 1];
      float a_a = bf2f((u16)(wv & 0xFFFF));
      float a_b = bf2f((u16)(wv >> 16));
      os[k*2]   = Ap + xs[k*2];
      Ap = (1.f + w_a)*Ap - w_a*a_a;
      os[k*2+1] = Ap + xs[k*2+1];
      Ap = (1.f + w_b)*Ap - w_b*a_b;
    }
    float4 o0, o1;
    o0.x=os[0]; o0.y=os[1]; o0.z=os[2]; o0.w=os[3];
    o1.x=os[4]; o1.y=os[5]; o1.z=os[6]; o1.w=os[7];
    *(float4*)&out[cbase + i*8]     = o0;
    *(float4*)&out[cbase + i*8 + 4] = o1;
  }
}

extern "C" void kernel_launch(void* const* d_in, const int* in_sizes, int n_in,
                              void* d_out, int out_size, void* d_ws, size_t ws_size,
                              hipStream_t stream){
  const float* x  = (const float*)d_in[0];
  const float* w1 = (const float*)d_in[1];
  const float* b1 = (const float*)d_in[2];
  const float* w2 = (const float*)d_in[3];
  const float* b2 = (const float*)d_in[4];
  const float* w3 = (const float*)d_in[5];
  const float* b3 = (const float*)d_in[6];
  float* out = (float*)d_out;

  // workspace carve: B(relu'd) 32MB | Bout 32MB | W1T 32KB | W2T 288KB
  u16* B    = (u16*)d_ws;
  u16* Bout = B    + (size_t)NPIX*CH;
  u16* W1T  = Bout + (size_t)NPIX*CH;
  u16* W2T  = W1T  + 16384;

  hipLaunchKernelGGL(k_prep,   dim3(640),  dim3(256), 0, stream, w1, w2, W1T, W2T);
  hipLaunchKernelGGL(k_phase1, dim3(1024), dim3(256), 0, stream, x, W1T, b1, B);
  for (int s = 0; s < 4; ++s)
    hipLaunchKernelGGL(k_phase2, dim3(512), dim3(256), 0, stream, B, Bout, W2T, b2, s);
  hipLaunchKernelGGL(k_phase3, dim3(1024), dim3(256), 0, stream, Bout, w3, b3, x, out);
}